// Round 1
// 248.902 us; speedup vs baseline: 1.0577x; 1.0577x over previous
//
#include <hip/hip_runtime.h>

// Multibin binary conv:  y = conv2d(sign(x), sum_m sign(W_m), SAME) + sum_m b_m
// x: [16,256,256,32] f32   W: [4,3,3,32,32] f32   b: [4,32] f32
// out: [16,256,256,32] f32
//
// Strategy: implicit GEMM with mfma_i32_32x32x32_i8 (exact: signs ±1 i8,
// wsum in {-4..4} i8, i32 accumulate, cvt to f32 at store).
//   A = im2col(sign(x)) as ±1 i8 (0 for SAME-padding halo)
//   B = wsumT[co][k], k = (dh*3+dw)*32 + ci
// 1-wave workgroups (64 thr): 32-col x 8-row strip, rolling 4-slot LDS row
// buffer, NO __syncthreads anywhere (intra-wave DS ordering suffices).
// Grid 4096 -> 16 blocks/CU = 4 waves/SIMD (vs previous 2), independent
// pipelines for MLP.  Per tap: one K=32 MFMA (9 per output row-tile).

#define RH      8
#define NSTAGE  34                  // 32 cols + 2 halo
#define PITCHB  48                  // bytes per pixel (32 ci + 16 pad; 16B-aligned frags)
#define SLOTB   (NSTAGE * PITCHB)   // 1632 B per row slot; 4 slots = 6528 B

typedef __attribute__((ext_vector_type(4)))  int i32x4;
typedef __attribute__((ext_vector_type(16))) int i32x16;

__device__ __forceinline__ unsigned int pack4(float4 v, bool ok) {
    // sign(x) as i8: +1 = 0x01, -1 = 0xFF; padding -> 0.  (f >= 0 handles -0.0 like the ref)
    if (!ok) return 0u;
    unsigned r = (v.x >= 0.0f) ? 0x01u : 0xFFu;
    r |= ((v.y >= 0.0f) ? 0x01u : 0xFFu) << 8;
    r |= ((v.z >= 0.0f) ? 0x01u : 0xFFu) << 16;
    r |= ((v.w >= 0.0f) ? 0x01u : 0xFFu) << 24;
    return r;
}

// ---------------- prep: wsT[co][288] i8 + bsum[32] f32 into d_ws ----------------
__global__ void prep_kernel(const float* __restrict__ W, const float* __restrict__ bias,
                            signed char* __restrict__ wsT, float* __restrict__ bsum) {
    int t = blockIdx.x * 256 + threadIdx.x;
    if (t < 9216) {
        int k   = t >> 5;          // 0..287 = tap*32 + ci
        int co  = t & 31;
        int tap = k >> 5;          // dh*3+dw
        int ci  = k & 31;
        float s = 0.0f;
        #pragma unroll
        for (int m = 0; m < 4; ++m) {
            float w = W[(m * 9 + tap) * 1024 + ci * 32 + co];
            s += (w >= 0.0f) ? 1.0f : -1.0f;
        }
        wsT[co * 288 + k] = (signed char)(int)s;   // exact, in {-4..4}
    }
    if (t < 32) {
        float s = 0.0f;
        #pragma unroll
        for (int m = 0; m < 4; ++m) s += bias[m * 32 + t];
        bsum[t] = s;
    }
}

__global__ __launch_bounds__(64, 4) void conv_kernel(const float* __restrict__ x,
                                                     const signed char* __restrict__ wsT,
                                                     const float* __restrict__ bsum,
                                                     float* __restrict__ out) {
    __shared__ __align__(16) unsigned char lds[4 * SLOTB];

    const int lane = threadIdx.x;     // single wave per block
    const int lrow = lane & 31;       // A: pixel row / B,D: cout column
    const int lk   = lane >> 5;       // K-half selector

    const int bs   = blockIdx.x;      // 4096 = 16 img x 32 rowstrips x 8 colstrips
    const int c0   = (bs & 7) * 32;
    const int r0   = ((bs >> 3) & 31) * RH;
    const int bimg = bs >> 8;

    // B fragments: lane holds B[k = lk*16 + j][n = lrow] = wsT[lrow][tap*32 + lk*16 + j]
    i32x4 bfrag[9];
    #pragma unroll
    for (int t = 0; t < 9; ++t)
        bfrag[t] = *(const i32x4*)(wsT + lrow * 288 + t * 32 + lk * 16);
    const float bsv = bsum[lrow];

    // pre-stage rows r0-1, r0, r0+1 -> slots 0,1,2 (intra-wave: no barrier needed)
    #pragma unroll
    for (int pre = 0; pre < 3; ++pre) {
        const int absrow = r0 - 1 + pre;
        const bool rowok = (absrow >= 0) && (absrow < 256);
        const float* rowp = x + (long)((bimg * 256 + absrow) * 256) * 32;
        unsigned char* dst = lds + pre * SLOTB;
        #pragma unroll
        for (int p = 0; p < 3; ++p) {
            int f = lane + p * 64;              // 136 chunks: 34 px x 4 (8 floats each)
            int pix = f >> 2, ch = f & 3;
            if (pix < NSTAGE) {
                int col = c0 - 1 + pix;
                bool ok = rowok && (col >= 0) && (col < 256);
                const float4* pp = (const float4*)(rowp + (long)col * 32 + ch * 8);
                float4 v0 = ok ? pp[0] : make_float4(0.f, 0.f, 0.f, 0.f);
                float4 v1 = ok ? pp[1] : make_float4(0.f, 0.f, 0.f, 0.f);
                *(uint2*)(dst + pix * PITCHB + ch * 8) =
                    make_uint2(pack4(v0, ok), pack4(v1, ok));
            }
        }
    }

    const int a_off = lrow * PITCHB + lk * 16;

    #pragma unroll 4
    for (int i = 0; i < RH; ++i) {
        const int r = r0 + i;
        const bool do_pf = (i < RH - 1);
        const int absrow = r + 2;                 // next-next row
        const bool rowok = do_pf && (absrow < 256);
        const float* rowp = x + (long)((bimg * 256 + absrow) * 256) * 32;

        // ---- issue prefetch loads (latency hides behind MFMA + store) ----
        float4 v0[3], v1[3];
        #pragma unroll
        for (int p = 0; p < 3; ++p) {
            int f = lane + p * 64;
            int pix = f >> 2, ch = f & 3;
            int col = c0 - 1 + pix;
            bool ok = rowok && (pix < NSTAGE) && (col >= 0) && (col < 256);
            const float4* pp = (const float4*)(rowp + (long)col * 32 + ch * 8);
            v0[p] = ok ? pp[0] : make_float4(0.f, 0.f, 0.f, 0.f);
            v1[p] = ok ? pp[1] : make_float4(0.f, 0.f, 0.f, 0.f);
        }

        // ---- compute output row r from slots (i, i+1, i+2) & 3 ----
        i32x16 acc = {};
        #pragma unroll
        for (int dh = 0; dh < 3; ++dh) {
            const unsigned char* sb = lds + ((i + dh) & 3) * SLOTB + a_off;
            #pragma unroll
            for (int dw = 0; dw < 3; ++dw) {
                i32x4 a = *(const i32x4*)(sb + dw * PITCHB);
                acc = __builtin_amdgcn_mfma_i32_32x32x32_i8(a, bfrag[dh * 3 + dw],
                                                            acc, 0, 0, 0);
            }
        }

        // ---- store: D col = lrow (cout), row = (reg&3)+8*(reg>>2)+4*lk (pixel) ----
        // nontemporal: don't let the streamed 134MB output evict x from L2/L3
        float* op = out + ((long)((bimg * 256 + r) * 256 + c0)) * 32 + lrow;
        #pragma unroll
        for (int reg = 0; reg < 16; ++reg) {
            int pr = (reg & 3) + 8 * (reg >> 2) + 4 * lk;
            __builtin_nontemporal_store((float)acc[reg] + bsv, op + pr * 32);
        }

        // ---- convert + LDS write of prefetched row into slot (i+3)&3 ----
        if (do_pf) {
            unsigned char* dst = lds + ((i + 3) & 3) * SLOTB;
            #pragma unroll
            for (int p = 0; p < 3; ++p) {
                int f = lane + p * 64;
                int pix = f >> 2, ch = f & 3;
                if (pix < NSTAGE) {
                    int col = c0 - 1 + pix;
                    bool ok = (absrow < 256) && (col >= 0) && (col < 256);
                    *(uint2*)(dst + pix * PITCHB + ch * 8) =
                        make_uint2(pack4(v0[p], ok), pack4(v1[p], ok));
                }
            }
        }
    }
}

extern "C" void kernel_launch(void* const* d_in, const int* in_sizes, int n_in,
                              void* d_out, int out_size, void* d_ws, size_t ws_size,
                              hipStream_t stream) {
    const float* x    = (const float*)d_in[0];   // [16,256,256,32]
    const float* W    = (const float*)d_in[1];   // [4,3,3,32,32]
    const float* bias = (const float*)d_in[2];   // [4,32]
    float* out = (float*)d_out;

    signed char* wsT = (signed char*)d_ws;              // 9216 B
    float* bsum = (float*)((char*)d_ws + 9216);         // 32 f32

    prep_kernel<<<36, 256, 0, stream>>>(W, bias, wsT, bsum);
    conv_kernel<<<4096, 64, 0, stream>>>(x, wsT, bsum, out);
}